// Round 1
// baseline (448.306 us; speedup 1.0000x reference)
//
#include <hip/hip_runtime.h>

#define B_   16
#define LQ   2048
#define LK   2048
#define DD   128
#define QB   64
#define KBT  64
#define NKT  (LK / KBT)
#define SCALE_ 0.08838834764831845f
#define DROPP  0.1f

typedef float f32x4 __attribute__((ext_vector_type(4)));
typedef __bf16 bf16x8 __attribute__((ext_vector_type(8)));
typedef unsigned short u16x8 __attribute__((ext_vector_type(8)));
typedef unsigned short u16x4 __attribute__((ext_vector_type(4)));

// float -> bf16 bits, round-to-nearest-even (manual: avoids any __bf16 cast codegen concerns)
static __device__ __forceinline__ unsigned short f2bu(float x) {
  unsigned int b = __builtin_bit_cast(unsigned int, x);
  b += 0x7FFFu + ((b >> 16) & 1u);
  return (unsigned short)(b >> 16);
}

// ---------- prepass 1: K f32 -> bf16 (same layout) ----------
__global__ __launch_bounds__(256) void cvt_k_kernel(const float* __restrict__ in,
                                                    unsigned short* __restrict__ out) {
  int i = blockIdx.x * 256 + threadIdx.x;
  f32x4 f = ((const f32x4*)in)[i];
  u16x4 o;
#pragma unroll
  for (int j = 0; j < 4; ++j) o[j] = f2bu(f[j]);
  ((u16x4*)out)[i] = o;
}

// ---------- prepass 2: V f32 [B][Lk][D] -> bf16 transposed [B][D][Lk] ----------
__global__ __launch_bounds__(256) void tr_v_kernel(const float* __restrict__ v,
                                                   unsigned short* __restrict__ vt) {
  __shared__ float tile[32][33];
  const int bid = blockIdx.x;
  const int b  = bid >> 8;          // 256 tiles per batch
  const int tk = (bid >> 2) & 63;   // Lk/32
  const int td = bid & 3;           // D/32
  const int t  = threadIdx.x;
  {
    int rk = t >> 3, c4 = (t & 7) * 4;
    f32x4 f = *(const f32x4*)(v + ((size_t)b * LK + tk * 32 + rk) * DD + td * 32 + c4);
#pragma unroll
    for (int j = 0; j < 4; ++j) tile[c4 + j][rk] = f[j];
  }
  __syncthreads();
  {
    int d = t >> 3, k4 = (t & 7) * 4;
    u16x4 o;
#pragma unroll
    for (int j = 0; j < 4; ++j) o[j] = f2bu(tile[d][k4 + j]);
    *(u16x4*)(vt + ((size_t)b * DD + td * 32 + d) * LK + tk * 32 + k4) = o;
  }
}

// ---------- flash attention with mask + reference column + deterministic dropout ----------
__global__ __launch_bounds__(256, 2) void attn_kernel(
    const float* __restrict__ q, const unsigned short* __restrict__ kbf,
    const unsigned short* __restrict__ vtb, const int* __restrict__ mask,
    const float* __restrict__ u, float* __restrict__ out)
{
  constexpr int KOFF = 0;          // K tile: 64 rows x 256B (swizzled)    = 16 KiB
  constexpr int VOFF = 16384;      // V^T tile: 128 rows x 128B (swizzled) = 16 KiB
  constexpr int POFF = 32768;      // P: 4 waves x 16 rows x 144B (72 bf16, +8 pad) = 9 KiB
  __shared__ __align__(16) unsigned char lds[32768 + 4 * 16 * 144];

  const int tid = threadIdx.x;
  const int w  = tid >> 6;
  const int l  = tid & 63;
  const int lo = l & 15, hi = l >> 4;

  // batch-pinned XCD swizzle: batch b always lands on XCD b&7 (K/V stay L2-local)
  const int wg = blockIdx.x;
  const int b  = (wg & 7) | ((wg >= 256) ? 8 : 0);
  const int qt = (wg >> 3) & 31;
  const int q0 = qt * QB;

  // ---- Q fragments (bf16, pre-scaled). A-layout: m = lo, k = kbi*32 + hi*8 + j
  bf16x8 qf[4];
  {
    const float* qrow = q + ((size_t)b * LQ + q0 + w * 16 + lo) * DD;
#pragma unroll
    for (int kbi = 0; kbi < 4; ++kbi) {
      int d0 = kbi * 32 + hi * 8;
      f32x4 f0 = *(const f32x4*)(qrow + d0);
      f32x4 f1 = *(const f32x4*)(qrow + d0 + 4);
      u16x8 a;
#pragma unroll
      for (int j = 0; j < 4; ++j) {
        a[j]     = f2bu(f0[j] * SCALE_);
        a[4 + j] = f2bu(f1[j] * SCALE_);
      }
      qf[kbi] = __builtin_bit_cast(bf16x8, a);
    }
  }

  const int* mrow = mask + b * LK;
  const float* ubase = u + ((size_t)b * LQ + q0 + w * 16 + hi * 4) * (size_t)(LK + 1);
  const unsigned short* kbase = kbf + (size_t)b * LK * DD;
  const unsigned short* vbase = vtb + (size_t)b * DD * LK;

  f32x4 acc[8];
#pragma unroll
  for (int i = 0; i < 8; ++i) acc[i] = (f32x4){0.f, 0.f, 0.f, 0.f};
  float lsum[4] = {0.f, 0.f, 0.f, 0.f};

  u16x8 kreg[4], vreg[4];

  auto load_tile = [&](int k0) {
#pragma unroll
    for (int i = 0; i < 4; ++i) {
      int c = tid + 256 * i;
      int rk = c >> 4, ck = c & 15;                 // K: 16 chunks/row of 16B
      kreg[i] = *(const u16x8*)(kbase + (size_t)(k0 + rk) * DD + ck * 8);
      int rv = c >> 3, cv = c & 7;                  // V^T: 8 chunks/row of 16B
      vreg[i] = *(const u16x8*)(vbase + (size_t)rv * LK + k0 + cv * 8);
    }
  };
  auto write_tile = [&]() {
#pragma unroll
    for (int i = 0; i < 4; ++i) {
      int c = tid + 256 * i;
      int rk = c >> 4, ck = c & 15;
      *(u16x8*)(&lds[KOFF + rk * 256 + ((ck ^ (rk & 7)) << 4)]) = kreg[i];
      int rv = c >> 3, cv = c & 7;
      *(u16x8*)(&lds[VOFF + rv * 128 + ((cv ^ (rv & 7)) << 4)]) = vreg[i];
    }
  };

  load_tile(0);

  for (int t = 0; t < NKT; ++t) {
    const int k0 = t * KBT;
    __syncthreads();                 // prev tile's LDS consumers done
    write_tile();
    if (t + 1 < NKT) load_tile(k0 + KBT);   // overlap next tile's HBM latency with compute
    __syncthreads();                 // tile staged

    // hoist u + mask loads ahead of MFMAs (latency hiding)
    float uval[4][4];
    int mv[4];
#pragma unroll
    for (int ct = 0; ct < 4; ++ct) {
      int col = k0 + ct * 16 + lo;
      mv[ct] = mrow[col];
#pragma unroll
      for (int reg = 0; reg < 4; ++reg)
        uval[ct][reg] = ubase[(size_t)reg * (LK + 1) + col];
    }

    // ---- QK^T, exp, mask, dropout, P -> LDS (wave-private, C-layout rows)
#pragma unroll
    for (int ct = 0; ct < 4; ++ct) {
      f32x4 s = (f32x4){0.f, 0.f, 0.f, 0.f};
#pragma unroll
      for (int kbi = 0; kbi < 4; ++kbi) {
        int r = ct * 16 + lo;        // local kk row; B-layout: n = lo, k = kbi*32+hi*8+j
        bf16x8 bk = *(const bf16x8*)(&lds[KOFF + r * 256 +
                                          ((kbi * 64 + hi * 16) ^ ((r & 7) << 4))]);
        s = __builtin_amdgcn_mfma_f32_16x16x32_bf16(qf[kbi], bk, s, 0, 0, 0);
      }
#pragma unroll
      for (int reg = 0; reg < 4; ++reg) {
        float p = __expf(s[reg]);    // max logit ~6: no max-subtraction needed (ref col anchors)
        p = mv[ct] ? p : 0.f;        // key-padding mask
        lsum[reg] += p;              // denominator: pre-dropout
        float pd = (uval[ct][reg] >= DROPP) ? p : 0.f;  // deterministic dropout
        *(unsigned short*)(&lds[POFF + (size_t)(w * 16 + hi * 4 + reg) * 144 +
                                (ct * 16 + lo) * 2]) = f2bu(pd);
      }
    }

    // ---- PV: A = P (rows m = lo), B = V^T
    bf16x8 pa[2];
#pragma unroll
    for (int kb2 = 0; kb2 < 2; ++kb2)
      pa[kb2] = *(const bf16x8*)(&lds[POFF + (w * 16 + lo) * 144 + (kb2 * 32 + hi * 8) * 2]);

#pragma unroll
    for (int ctd = 0; ctd < 8; ++ctd) {
#pragma unroll
      for (int kb2 = 0; kb2 < 2; ++kb2) {
        int rv = ctd * 16 + lo;      // V^T row = d; B-layout: n = lo(d), k = kb2*32+hi*8+j
        bf16x8 bv = *(const bf16x8*)(&lds[VOFF + rv * 128 +
                                          ((kb2 * 64 + hi * 16) ^ ((rv & 7) << 4))]);
        acc[ctd] = __builtin_amdgcn_mfma_f32_16x16x32_bf16(pa[kb2], bv, acc[ctd], 0, 0, 0);
      }
    }
  }

  // ---- epilogue: reduce row-sums over the 16 col-lanes, normalize, write f32
  float* outp = out + ((size_t)b * LQ + q0 + w * 16 + hi * 4) * DD + lo;
#pragma unroll
  for (int reg = 0; reg < 4; ++reg) {
    float v = lsum[reg];
    v += __shfl_xor(v, 1);
    v += __shfl_xor(v, 2);
    v += __shfl_xor(v, 4);
    v += __shfl_xor(v, 8);
    float inv = 1.0f / (0.9f * (v + 1.0f));   // +1 = reference column exp(0); /0.9 = dropout scale
#pragma unroll
    for (int ctd = 0; ctd < 8; ++ctd)
      outp[(size_t)reg * DD + ctd * 16] = acc[ctd][reg] * inv;
  }
}

extern "C" void kernel_launch(void* const* d_in, const int* in_sizes, int n_in,
                              void* d_out, int out_size, void* d_ws, size_t ws_size,
                              hipStream_t stream) {
  const float* q    = (const float*)d_in[0];
  const float* k    = (const float*)d_in[1];
  const float* v    = (const float*)d_in[2];
  const int*   mask = (const int*)d_in[3];
  const float* u    = (const float*)d_in[4];
  float* out = (float*)d_out;

  unsigned short* kb = (unsigned short*)d_ws;                 // 8.4 MB
  unsigned short* vt = kb + (size_t)B_ * LK * DD;             // 8.4 MB

  cvt_k_kernel<<<(B_ * LK * DD / 4) / 256, 256, 0, stream>>>(k, kb);
  tr_v_kernel<<<B_ * (LK / 32) * (DD / 32), 256, 0, stream>>>(v, vt);
  attn_kernel<<<B_ * (LQ / QB), 256, 0, stream>>>(q, kb, vt, mask, u, out);
}